// Round 8
// baseline (842.194 us; speedup 1.0000x reference)
//
#include <hip/hip_runtime.h>
#include <math.h>

// ---------------- ws layout (floats) ----------------
static const size_t OFF_POOLED = 0;                     // 2048*90
static const size_t OFF_EMB1   = 184320;                // 2048*4096 (reused for fe1)
static const size_t OFF_ACC1   = OFF_EMB1 + 8388608;    // 2048*64
static const size_t OFF_ACC2   = OFF_ACC1 + 131072;     // 2048*64
static const size_t OFF_X1     = OFF_ACC2 + 131072;     // 2048*256
static const size_t OFF_FPOOL  = OFF_X1 + 524288;       // 2048*90
static const size_t OFF_H1     = OFF_FPOOL + 184320;    // 2048*64
static const size_t OFF_C1     = OFF_H1 + 131072;       // 2048*64
static const size_t OFF_H2     = OFF_C1 + 131072;       // 2048*32
static const size_t OFF_C2     = OFF_H2 + 65536;        // 2048*32

typedef _Float16 h2f_t __attribute__((ext_vector_type(2)));

__device__ __forceinline__ float fsig(float x) {
    return __builtin_amdgcn_rcpf(1.0f + __expf(-x));
}
__device__ __forceinline__ float ftanh(float x) {
    return 1.0f - 2.0f * __builtin_amdgcn_rcpf(__expf(2.0f * x) + 1.0f);
}

// f32 += f16x2 · f16x2 (f32 accumulate). v_dot2_f32_f16 on gfx950.
__device__ __forceinline__ float fdot2(h2f_t a, h2f_t b, float c) {
#if __has_builtin(__builtin_amdgcn_fdot2)
    return __builtin_amdgcn_fdot2(a, b, c, false);
#else
    return c + (float)a.x * (float)b.x + (float)a.y * (float)b.y;
#endif
}
__device__ __forceinline__ h2f_t h2pack(float x, float y) {
    h2f_t r; r.x = (_Float16)x; r.y = (_Float16)y; return r;
}
__device__ __forceinline__ h2f_t h2bits(int v) {
    return __builtin_bit_cast(h2f_t, v);
}
// wave-local LDS fence variants
__device__ __forceinline__ void lds_fence() {
    asm volatile("s_waitcnt lgkmcnt(0)" ::: "memory");
}
// lane-pair exchange: lane l <-> lane l^1 (BitMode xor=1, and=0x1F)
__device__ __forceinline__ float swz_xor1(float x) {
    return __builtin_bit_cast(float,
        __builtin_amdgcn_ds_swizzle(__builtin_bit_cast(int, x), 0x041F));
}
// lane l <-> lane l^16 within each 32-lane group (BitMode xor=16)
__device__ __forceinline__ float swz_xor16(float x) {
    return __builtin_bit_cast(float,
        __builtin_amdgcn_ds_swizzle(__builtin_bit_cast(int, x), 0x401F));
}
// gfx950 VALU: x.upper32 <- y.lower32 ; y.lower32 <- x.upper32 (verified in r1+)
__device__ __forceinline__ void permswap(float& x, float& y) {
    asm volatile("v_permlane32_swap_b32 %0, %1" : "+v"(x), "+v"(y));
}

// ---------------- SPP: adaptive max pool levels 4,3,2,1 ----------------
__global__ __launch_bounds__(256) void spp_kernel(const float* __restrict__ frames,
                                                  float* __restrict__ out_pooled,
                                                  float* __restrict__ ws_pooled) {
    __shared__ __align__(16) float img[9216];
    __shared__ float p4[16], p3[9];
    int blk = blockIdx.x;          // n*3 + c
    int n = blk / 3, c = blk % 3;
    const float* src = frames + (size_t)blk * 9216;
    int tid = threadIdx.x;
    const float4* s4 = (const float4*)src;
    float4* i4 = (float4*)img;
#pragma unroll
    for (int j = 0; j < 9; ++j) i4[tid + 256 * j] = s4[tid + 256 * j];
    __syncthreads();
    // level 4: 16 regions of 24x24; 16 lanes/region read consecutive elements
    {
        int r = tid >> 4, i = tid & 15;
        int ri = r >> 2, rj = r & 3;
        const float* base = &img[(24 * ri) * 96 + 24 * rj];
        float m = -3.402823466e38f;
#pragma unroll 6
        for (int k = 0; k < 36; ++k) {
            int e = i + 16 * k;          // 0..575
            int row = e / 24;
            int col = e - row * 24;
            m = fmaxf(m, base[row * 96 + col]);
        }
#pragma unroll
        for (int sh = 8; sh >= 1; sh >>= 1) m = fmaxf(m, __shfl_xor(m, sh));
        if (i == 0) p4[r] = m;
    }
    // level 3: 9 regions of 32x32; 16 lanes/region, consecutive elements
    if (tid < 144) {
        int r = tid >> 4, i = tid & 15;
        int ri = r / 3, rj = r % 3;
        const float* base = &img[(32 * ri) * 96 + 32 * rj];
        float m = -3.402823466e38f;
#pragma unroll 8
        for (int k = 0; k < 64; ++k) {
            int e = i + 16 * k;          // 0..1023
            int row = e >> 5, col = e & 31;
            m = fmaxf(m, base[row * 96 + col]);
        }
#pragma unroll
        for (int sh = 8; sh >= 1; sh >>= 1) m = fmaxf(m, __shfl_xor(m, sh));
        if (i == 0) p3[r] = m;
    }
    __syncthreads();
    if (tid < 30) {
        float v; int off;
        if (tid < 16) { v = p4[tid]; off = c * 16 + tid; }
        else if (tid < 25) { int q = tid - 16; v = p3[q]; off = 48 + c * 9 + q; }
        else if (tid < 29) {
            int q = tid - 25; int i2 = q >> 1, j2 = q & 1;
            v = fmaxf(fmaxf(p4[(2 * i2) * 4 + 2 * j2], p4[(2 * i2) * 4 + 2 * j2 + 1]),
                      fmaxf(p4[(2 * i2 + 1) * 4 + 2 * j2], p4[(2 * i2 + 1) * 4 + 2 * j2 + 1]));
            off = 75 + c * 4 + q;
        } else {
            float m = p4[0];
#pragma unroll
            for (int q = 1; q < 16; ++q) m = fmaxf(m, p4[q]);
            v = m; off = 87 + c;
        }
        out_pooled[(size_t)n * 90 + off] = v;
        ws_pooled[(size_t)n * 90 + off] = v;
    }
}

// ---------------- GEMM: Y(2048,4096) = relu(X(2048,90) @ W(4096,90)^T + b) ----------------
__global__ __launch_bounds__(256) void gemm90_kernel(const float* __restrict__ X,
                                                     const float* __restrict__ W,
                                                     const float* __restrict__ bias,
                                                     float* __restrict__ Y) {
    __shared__ __align__(16) float Xs[32][132];
    __shared__ __align__(16) float Ws[32][132];
    int tid = threadIdx.x;
    int R0 = blockIdx.x * 128, C0 = blockIdx.y * 128;
    int r0t = (tid >> 4) * 8, c0t = (tid & 15) * 8;
    float acc[8][8];
#pragma unroll
    for (int i = 0; i < 8; ++i)
#pragma unroll
        for (int j = 0; j < 8; ++j) acc[i][j] = 0.f;

    for (int k0 = 0; k0 < 96; k0 += 32) {
#pragma unroll
        for (int j = 0; j < 4; ++j) {
            int idx = tid + 256 * j;
            int row = idx & 127, q = idx >> 7;
            int kg = k0 + 4 * q;
            const float2* p = (const float2*)&X[(size_t)(R0 + row) * 90 + kg];
            float2 a = p[0], b = p[1];
            Xs[4 * q + 0][row] = a.x; Xs[4 * q + 1][row] = a.y;
            Xs[4 * q + 2][row] = b.x; Xs[4 * q + 3][row] = b.y;
        }
#pragma unroll
        for (int j = 0; j < 4; ++j) {
            int idx = tid + 256 * j;
            int col = idx & 127, q = idx >> 7;
            int kg = k0 + 4 * q;
            float v0, v1, v2, v3;
            if (kg + 3 < 90) {
                const float2* p = (const float2*)&W[(size_t)(C0 + col) * 90 + kg];
                float2 a = p[0], b = p[1];
                v0 = a.x; v1 = a.y; v2 = b.x; v3 = b.y;
            } else {
                const float* p = &W[(size_t)(C0 + col) * 90];
                v0 = (kg + 0 < 90) ? p[kg + 0] : 0.f;
                v1 = (kg + 1 < 90) ? p[kg + 1] : 0.f;
                v2 = (kg + 2 < 90) ? p[kg + 2] : 0.f;
                v3 = (kg + 3 < 90) ? p[kg + 3] : 0.f;
            }
            Ws[4 * q + 0][col] = v0; Ws[4 * q + 1][col] = v1;
            Ws[4 * q + 2][col] = v2; Ws[4 * q + 3][col] = v3;
        }
        __syncthreads();
#pragma unroll 8
        for (int kk = 0; kk < 32; ++kk) {
            float4 xa = *(const float4*)&Xs[kk][r0t];
            float4 xb = *(const float4*)&Xs[kk][r0t + 4];
            float4 wa = *(const float4*)&Ws[kk][c0t];
            float4 wb = *(const float4*)&Ws[kk][c0t + 4];
            float xr[8] = {xa.x, xa.y, xa.z, xa.w, xb.x, xb.y, xb.z, xb.w};
            float wc[8] = {wa.x, wa.y, wa.z, wa.w, wb.x, wb.y, wb.z, wb.w};
#pragma unroll
            for (int i = 0; i < 8; ++i)
#pragma unroll
                for (int j = 0; j < 8; ++j) acc[i][j] += xr[i] * wc[j];
        }
        __syncthreads();
    }
    float4 ba = *(const float4*)&bias[C0 + c0t];
    float4 bb = *(const float4*)&bias[C0 + c0t + 4];
    float bs[8] = {ba.x, ba.y, ba.z, ba.w, bb.x, bb.y, bb.z, bb.w};
#pragma unroll
    for (int i = 0; i < 8; ++i) {
        float4 o0, o1;
        o0.x = fmaxf(acc[i][0] + bs[0], 0.f); o0.y = fmaxf(acc[i][1] + bs[1], 0.f);
        o0.z = fmaxf(acc[i][2] + bs[2], 0.f); o0.w = fmaxf(acc[i][3] + bs[3], 0.f);
        o1.x = fmaxf(acc[i][4] + bs[4], 0.f); o1.y = fmaxf(acc[i][5] + bs[5], 0.f);
        o1.z = fmaxf(acc[i][6] + bs[6], 0.f); o1.w = fmaxf(acc[i][7] + bs[7], 0.f);
        *(float4*)&Y[(size_t)(R0 + r0t + i) * 4096 + C0 + c0t] = o0;
        *(float4*)&Y[(size_t)(R0 + r0t + i) * 4096 + C0 + c0t + 4] = o1;
    }
}

// ---------------- GEMM: acc(2048,64) += X(2048,4096) @ W(64,4096)^T, K-split + atomics ----------------
__global__ __launch_bounds__(256) void gemmk_kernel(const float* __restrict__ X,
                                                    const float* __restrict__ W,
                                                    float* __restrict__ acc_out) {
    __shared__ __align__(16) float Xs[32][132];
    __shared__ __align__(16) float Ws[32][68];
    int tid = threadIdx.x;
    int R0 = blockIdx.x * 128;
    int K0 = blockIdx.y * 256;
    int r0t = (tid >> 4) * 8, c0t = (tid & 15) * 4;
    float acc[8][4];
#pragma unroll
    for (int i = 0; i < 8; ++i)
#pragma unroll
        for (int j = 0; j < 4; ++j) acc[i][j] = 0.f;

    for (int k0 = K0; k0 < K0 + 256; k0 += 32) {
#pragma unroll
        for (int j = 0; j < 4; ++j) {
            int idx = tid + 256 * j;
            int row = idx & 127, q = idx >> 7;
            float4 a = *(const float4*)&X[(size_t)(R0 + row) * 4096 + k0 + 4 * q];
            Xs[4 * q + 0][row] = a.x; Xs[4 * q + 1][row] = a.y;
            Xs[4 * q + 2][row] = a.z; Xs[4 * q + 3][row] = a.w;
        }
#pragma unroll
        for (int j = 0; j < 2; ++j) {
            int idx = tid + 256 * j;
            int col = idx & 63, q = idx >> 6;
            float4 a = *(const float4*)&W[(size_t)col * 4096 + k0 + 4 * q];
            Ws[4 * q + 0][col] = a.x; Ws[4 * q + 1][col] = a.y;
            Ws[4 * q + 2][col] = a.z; Ws[4 * q + 3][col] = a.w;
        }
        __syncthreads();
#pragma unroll 8
        for (int kk = 0; kk < 32; ++kk) {
            float4 xa = *(const float4*)&Xs[kk][r0t];
            float4 xb = *(const float4*)&Xs[kk][r0t + 4];
            float4 wa = *(const float4*)&Ws[kk][c0t];
            float xr[8] = {xa.x, xa.y, xa.z, xa.w, xb.x, xb.y, xb.z, xb.w};
            float wc[4] = {wa.x, wa.y, wa.z, wa.w};
#pragma unroll
            for (int i = 0; i < 8; ++i)
#pragma unroll
                for (int j = 0; j < 4; ++j) acc[i][j] += xr[i] * wc[j];
        }
        __syncthreads();
    }
#pragma unroll
    for (int i = 0; i < 8; ++i)
#pragma unroll
        for (int j = 0; j < 4; ++j)
            atomicAdd(&acc_out[(size_t)(R0 + r0t + i) * 64 + c0t + j], acc[i][j]);
}

// ---------------- X1 = relu(acc1 + fc7_b) @ wih1^T + bih1 + bhh1  -> (2048,256) ----------------
__global__ __launch_bounds__(256) void x1_kernel(const float* __restrict__ acc1,
                                                 const float* __restrict__ fc7_b,
                                                 const float* __restrict__ wih1,
                                                 const float* __restrict__ bih1,
                                                 const float* __restrict__ bhh1,
                                                 float* __restrict__ X1) {
    __shared__ __align__(16) float xr[8][64];
    int tid = threadIdx.x;
    int R0 = blockIdx.x * 8;
#pragma unroll
    for (int j = 0; j < 2; ++j) {
        int idx = tid + 256 * j;
        int r = idx >> 6, k = idx & 63;
        xr[r][k] = fmaxf(acc1[(size_t)(R0 + r) * 64 + k] + fc7_b[k], 0.f);
    }
    __syncthreads();
    int u = tid;
    float w[64];
#pragma unroll
    for (int q = 0; q < 16; ++q) {
        float4 a = *(const float4*)&wih1[(size_t)u * 64 + 4 * q];
        w[4 * q] = a.x; w[4 * q + 1] = a.y; w[4 * q + 2] = a.z; w[4 * q + 3] = a.w;
    }
    float bias = bih1[u] + bhh1[u];
    for (int r = 0; r < 8; ++r) {
        float g = bias;
#pragma unroll
        for (int k = 0; k < 64; ++k) g += w[k] * xr[r][k];
        X1[(size_t)(R0 + r) * 256 + u] = g;
    }
}

// ---------------- sequential 2-layer LSTM; FOUR WAVES per batch element ----------------
// Unit-split (NOT partial-split): each wave owns complete gate-rows, so no cross-wave
// partial handoff. waves 0/1 = L1 units 0-31 / 32-63 (lane pair per unit: p=0 holds
// rows {u,128+u} (i,g), p=1 holds {64+u,192+u} (f,o) -> 64 dot2/lane, HALF of the old
// critical wave). waves 2/3 = L2 units 0-15 / 16-31 (1 gate-row/lane -> 48 dot2).
// Gate reunion is IN-WAVE: L1 one ds_swizzle xor-1; L2 swizzle xor-16 + 2 permlane32_swap.
// Cell computed redundantly in the lanes sharing a unit (identical inputs -> identical c).
// h1h AND h2h double-buffered; each wave pre-reads its OWN half before the barrier
// (same-wave in-order DS) and the other wave's half after it. One s_barrier per step.
// Rationale: measured ~6-8cy/inst SIMD issue in this 1-wave/SIMD regime (r5/r6/r7) =>
// critical-wave instruction count is the only lever; this halves it.
__global__ __launch_bounds__(256, 1) void seq_kernel(const float* __restrict__ X1,
                                                     const float* __restrict__ whh1,
                                                     const float* __restrict__ wih2,
                                                     const float* __restrict__ whh2,
                                                     const float* __restrict__ bih2,
                                                     const float* __restrict__ bhh2,
                                                     float* __restrict__ h1_all, float* __restrict__ c1_all,
                                                     float* __restrict__ h2_all, float* __restrict__ c2_all) {
    __shared__ __align__(16) _Float16 h1h[2][64];
    __shared__ __align__(16) _Float16 h2h[2][32];
    const int tid = threadIdx.x;
    const int wid = tid >> 6;
    const int l = tid & 63;
    const size_t n0 = (size_t)blockIdx.x * 256;
    const float* xp = X1 + n0 * 256;

    if (wid < 2) {
        // ================= waves 0,1: layer-1 recurrence (units 32*wid .. 32*wid+31) ==
        const int w = wid;
        const int j = l >> 1, p = l & 1;
        const int u = 32 * w + j;
        const int rA = p ? 64 + u : u;          // f : i
        const int rB = p ? 192 + u : 128 + u;   // o : g
        h2f_t wA[32], wB[32];
#pragma unroll
        for (int q = 0; q < 32; ++q) {
            wA[q] = h2pack(whh1[(size_t)rA * 64 + 2 * q], whh1[(size_t)rA * 64 + 2 * q + 1]);
            wB[q] = h2pack(whh1[(size_t)rB * 64 + 2 * q], whh1[(size_t)rB * 64 + 2 * q + 1]);
        }
        float c1;
        {   // prologue: t=0 from X1 row 0; h1(-1)=c1(-1)=0. Both p lanes redundant.
            float xi = xp[u], xg = xp[128 + u], xo = xp[192 + u];
            c1 = fsig(xi) * ftanh(xg);
            float h1n = fsig(xo) * ftanh(c1);
            if (p == 0) {
                h1h[0][u] = (_Float16)h1n;
                h1_all[n0 * 64 + u] = h1n;
                c1_all[n0 * 64 + u] = c1;
            }
        }
        // 2-deep X prefetch of this lane's two gate inputs (rows t+1)
        float xA0 = xp[256 + rA], xB0 = xp[256 + rB];      // for t=0
        float xA1 = xp[512 + rA], xB1 = xp[512 + rB];      // for t=1
        int4 hv[8];
        {   // pre-read own half of h1(0) (in-order after own write)
            const int4* hb = (const int4*)&h1h[0][0];
#pragma unroll
            for (int q = 0; q < 4; ++q) hv[4 * w + q] = hb[4 * w + q];
        }
        lds_fence();
        __builtin_amdgcn_s_barrier();
        {   // other wave's half, visible after barrier
            const int4* hb = (const int4*)&h1h[0][0];
            const int o = 4 * (1 - w);
#pragma unroll
            for (int q = 0; q < 4; ++q) hv[o + q] = hb[o + q];
        }

#pragma unroll 2
        for (int t = 0; t < 256; ++t) {
            float xAc = (t & 1) ? xA1 : xA0;
            float xBc = (t & 1) ? xB1 : xB0;
            {   // refill with row t+3 (clamped; tail values unused)
                int tr = (t + 3 < 256) ? (t + 3) : 255;
                float nA = xp[(size_t)tr * 256 + rA];
                float nB = xp[(size_t)tr * 256 + rB];
                if (t & 1) { xA1 = nA; xB1 = nB; } else { xA0 = nA; xB0 = nB; }
            }
            // 64 dot2, 8 chains (4 per row), same-chain spacing 8 insts
            float a0 = xAc, a1 = 0.f, a2 = 0.f, a3 = 0.f;
            float b0 = xBc, b1 = 0.f, b2 = 0.f, b3 = 0.f;
#pragma unroll
            for (int q = 0; q < 8; ++q) {
                int4 v = hv[q];
                h2f_t h0 = h2bits(v.x), h1_ = h2bits(v.y), h2_ = h2bits(v.z), h3 = h2bits(v.w);
                a0 = fdot2(wA[4 * q],     h0,  a0); b0 = fdot2(wB[4 * q],     h0,  b0);
                a1 = fdot2(wA[4 * q + 1], h1_, a1); b1 = fdot2(wB[4 * q + 1], h1_, b1);
                a2 = fdot2(wA[4 * q + 2], h2_, a2); b2 = fdot2(wB[4 * q + 2], h2_, b2);
                a3 = fdot2(wA[4 * q + 3], h3,  a3); b3 = fdot2(wB[4 * q + 3], h3,  b3);
            }
            float sA = (a0 + a1) + (a2 + a3);   // p=0: i-sum   p=1: f-sum
            float sB = (b0 + b1) + (b2 + b3);   // p=0: g-sum   p=1: o-sum
            // lane-pair exchange: partner's two sums
            float swA = swz_xor1(sA);
            float swB = swz_xor1(sB);
            float gi = p ? swA : sA;
            float gf = p ? sA : swA;
            float gg = p ? swB : sB;
            float go = p ? sB : swB;
            // L1 cell (redundant in both p lanes; identical inputs => identical c1)
            c1 = fsig(gf) * c1 + fsig(gi) * ftanh(gg);
            float h1n = fsig(go) * ftanh(c1);
            if (p == 0) {
                h1h[(t + 1) & 1][u] = (_Float16)h1n;
                if (t < 255) {
                    h1_all[(n0 + t + 1) * 64 + u] = h1n;
                    c1_all[(n0 + t + 1) * 64 + u] = c1;
                }
            }
            {   // pre-read own half of h1(t+1) (in-order after the write above)
                const int4* hb = (const int4*)&h1h[(t + 1) & 1][0];
#pragma unroll
                for (int q = 0; q < 4; ++q) hv[4 * w + q] = hb[4 * w + q];
            }
            // outstanding DS: 1 write + 4 reads; retire the (older) write so the other
            // waves see h1(t+1) after the barrier, without draining the pre-reads
            asm volatile("s_waitcnt lgkmcnt(4)" ::: "memory");
            __builtin_amdgcn_s_barrier();
            {   // other wave's half of h1(t+1)
                const int4* hb = (const int4*)&h1h[(t + 1) & 1][0];
                const int o = 4 * (1 - w);
#pragma unroll
                for (int q = 0; q < 4; ++q) hv[o + q] = hb[o + q];
            }
        }
    } else {
        // ================= waves 2,3: layer-2 (units 16*(wid-2) .. +15) =============
        const int w2 = wid - 2;
        const int g = l >> 4, j = l & 15;      // gate 0..3 (i,f,g,o), unit-in-wave
        const int v = 16 * w2 + j;             // global L2 unit
        const int row = 32 * g + v;            // gate-row of wih2/whh2 (128 rows)
        h2f_t wa[32], wb[16];
#pragma unroll
        for (int q = 0; q < 32; ++q)
            wa[q] = h2pack(wih2[(size_t)row * 64 + 2 * q], wih2[(size_t)row * 64 + 2 * q + 1]);
#pragma unroll
        for (int q = 0; q < 16; ++q)
            wb[q] = h2pack(whh2[(size_t)row * 32 + 2 * q], whh2[(size_t)row * 32 + 2 * q + 1]);
        const float bias = bih2[row] + bhh2[row];
        const bool lo = (l < 32);
        float c2 = 0.f;
        if (w2 == 0 && l < 32) h2h[0][l] = (_Float16)0.f;   // h2(-1) = 0
        lds_fence();
        __builtin_amdgcn_s_barrier();

        for (int t = 0; t < 256; ++t) {
            // reads at top: h1(t) full (8x b128) + h2(t-1) full (2x b128)
            int4 hv[8];
            {
                const int4* hb = (const int4*)&h1h[t & 1][0];
#pragma unroll
                for (int q = 0; q < 8; ++q) hv[q] = hb[q];
            }
            int4 gv[2];
            {
                const int4* gb = (const int4*)&h2h[t & 1][0];
                gv[0] = gb[0]; gv[1] = gb[1];
            }
            // 48 dot2: 16 over h2 (4 chains), 32 over h1 (4 chains)
            float s4 = 0.f, s5 = 0.f, s6 = 0.f, s7 = 0.f;
#pragma unroll
            for (int q = 0; q < 2; ++q) {
                int4 uq = gv[q];
                h2f_t g0 = h2bits(uq.x), g1 = h2bits(uq.y), g2 = h2bits(uq.z), g3 = h2bits(uq.w);
                s4 = fdot2(wb[8 * q],     g0, s4); s5 = fdot2(wb[8 * q + 1], g1, s5);
                s6 = fdot2(wb[8 * q + 2], g2, s6); s7 = fdot2(wb[8 * q + 3], g3, s7);
                s4 = fdot2(wb[8 * q + 4], g0, s4); s5 = fdot2(wb[8 * q + 5], g1, s5);
                s6 = fdot2(wb[8 * q + 6], g2, s6); s7 = fdot2(wb[8 * q + 7], g3, s7);
            }
            float s0 = bias, s1 = 0.f, s2 = 0.f, s3 = 0.f;
#pragma unroll
            for (int q = 0; q < 8; ++q) {
                int4 vq = hv[q];
                h2f_t h0 = h2bits(vq.x), h1_ = h2bits(vq.y), h2_ = h2bits(vq.z), h3 = h2bits(vq.w);
                s0 = fdot2(wa[4 * q],     h0,  s0); s1 = fdot2(wa[4 * q + 1], h1_, s1);
                s2 = fdot2(wa[4 * q + 2], h2_, s2); s3 = fdot2(wa[4 * q + 3], h3,  s3);
            }
            float s = ((s0 + s1) + (s2 + s3)) + ((s4 + s5) + (s6 + s7));
            // gate reunion: xor-16 pairs (i<->f, g<->o), then 2 permlane32_swap
            float t1 = swz_xor16(s);
            float X1v = (g & 1) ? t1 : s;   // lower lanes: i ; upper lanes: g
            float X2v = (g & 1) ? s : t1;   // lower lanes: f ; upper lanes: o
            float a_ = X1v, b_ = X2v;
            permswap(a_, b_);               // a_: lo=i, up=f   b_: lo=g, up=o
            float c_ = X2v, d_ = X1v;
            permswap(c_, d_);               // c_: lo=f, up=i   d_: lo=o, up=g
            float gi = lo ? a_ : c_;
            float gf = lo ? c_ : a_;
            float gg = lo ? b_ : d_;
            float go = lo ? d_ : b_;
            // L2 cell (redundant x4 lanes; identical inputs => identical c2)
            c2 = fsig(gf) * c2 + fsig(gi) * ftanh(gg);
            float h2n = fsig(go) * ftanh(c2);
            if (g == 0) {
                h2h[(t + 1) & 1][v] = (_Float16)h2n;
                h2_all[(n0 + t) * 32 + v] = h2n;
                c2_all[(n0 + t) * 32 + v] = c2;
            }
            lds_fence();   // retire h2h write before barrier (cross-wave visibility)
            __builtin_amdgcn_s_barrier();
        }
    }
}

// ---------------- fpool + progress (parallel over all 2048 rows) ----------------
__global__ __launch_bounds__(256) void fpool_kernel(const float* __restrict__ h2_all,
                                                    const float* __restrict__ fw,
                                                    const float* __restrict__ fb,
                                                    const float* __restrict__ fc8_w,
                                                    const float* __restrict__ fc8_b,
                                                    float* __restrict__ fpool_ws,
                                                    float* __restrict__ out_fpooled,
                                                    float* __restrict__ out_progress) {
    __shared__ __align__(16) float h2t[16][32];
    __shared__ float fwl[2880];
    int tid = threadIdx.x;
    int R0 = blockIdx.x * 16;
#pragma unroll
    for (int j = 0; j < 2; ++j) {
        int idx = tid + 256 * j;
        int r = idx >> 5, k = idx & 31;
        h2t[r][k] = h2_all[(size_t)(R0 + r) * 32 + k];
    }
    for (int idx = tid; idx < 2880; idx += 256) fwl[idx] = fw[idx];
    __syncthreads();
    for (int j = 0; j < 6; ++j) {
        int idx = tid + 256 * j;
        if (idx < 1440) {
            int r = idx / 90, cc = idx % 90;
            float g = fb[cc];
#pragma unroll
            for (int k = 0; k < 32; ++k) g += h2t[r][k] * fwl[cc * 32 + k];
            fpool_ws[(size_t)(R0 + r) * 90 + cc] = g;
            out_fpooled[(size_t)(R0 + r) * 90 + cc] = g;
        }
    }
    if (tid < 16) {
        float g = fc8_b[0];
#pragma unroll
        for (int k = 0; k < 32; ++k) g += h2t[tid][k] * fc8_w[k];
        out_progress[R0 + tid] = fsig(g);
    }
}

// ---------------- forecast LSTM cells + fprogress (parallel over all 2048 rows) ----------------
__global__ __launch_bounds__(256) void fh_kernel(const float* __restrict__ acc2,
                                                 const float* __restrict__ fc7_b,
                                                 const float* __restrict__ h1_all,
                                                 const float* __restrict__ c1_all,
                                                 const float* __restrict__ h2_all,
                                                 const float* __restrict__ c2_all,
                                                 const float* __restrict__ wih1,
                                                 const float* __restrict__ whh1,
                                                 const float* __restrict__ bih1,
                                                 const float* __restrict__ bhh1,
                                                 const float* __restrict__ wih2,
                                                 const float* __restrict__ whh2,
                                                 const float* __restrict__ bih2,
                                                 const float* __restrict__ bhh2,
                                                 const float* __restrict__ fc8_w,
                                                 const float* __restrict__ fc8_b,
                                                 float* __restrict__ out_fprog) {
    __shared__ __align__(16) float xcat[8][128];   // [fe2 | h1]
    __shared__ float g1f[8][256];
    __shared__ __align__(16) float x2c[8][96];     // [fh1 | h2]
    __shared__ float g2f[8][128];
    __shared__ __align__(16) float fh2s[8][32];
    int tid = threadIdx.x;
    int R0 = blockIdx.x * 8;
#pragma unroll
    for (int j = 0; j < 4; ++j) {
        int idx = tid + 256 * j;
        int r = idx >> 7, k = idx & 127;
        float v;
        if (k < 64) v = fmaxf(acc2[(size_t)(R0 + r) * 64 + k] + fc7_b[k], 0.f);
        else v = h1_all[(size_t)(R0 + r) * 64 + (k - 64)];
        xcat[r][k] = v;
    }
    {
        int r = tid >> 5, k = tid & 31;
        x2c[r][64 + k] = h2_all[(size_t)(R0 + r) * 32 + k];
    }
    __syncthreads();
    {   // gates1f: 256 units, thread per unit, 8 rows
        int u = tid;
        float wa[64], wb[64];
#pragma unroll
        for (int q = 0; q < 16; ++q) {
            float4 a = *(const float4*)&wih1[(size_t)u * 64 + 4 * q];
            wa[4 * q] = a.x; wa[4 * q + 1] = a.y; wa[4 * q + 2] = a.z; wa[4 * q + 3] = a.w;
            float4 b = *(const float4*)&whh1[(size_t)u * 64 + 4 * q];
            wb[4 * q] = b.x; wb[4 * q + 1] = b.y; wb[4 * q + 2] = b.z; wb[4 * q + 3] = b.w;
        }
        float bias = bih1[u] + bhh1[u];
        for (int r = 0; r < 8; ++r) {
            float g = bias;
#pragma unroll
            for (int k = 0; k < 64; ++k) g += wa[k] * xcat[r][k];
#pragma unroll
            for (int k = 0; k < 64; ++k) g += wb[k] * xcat[r][64 + k];
            g1f[r][u] = g;
        }
    }
    __syncthreads();
#pragma unroll
    for (int j = 0; j < 2; ++j) {   // fh1 elementwise: 512 tasks
        int idx = tid + 256 * j;
        int r = idx >> 6, h = idx & 63;
        float gi = g1f[r][h], gf = g1f[r][64 + h], gg = g1f[r][128 + h], go = g1f[r][192 + h];
        float c1v = c1_all[(size_t)(R0 + r) * 64 + h];
        float c = fsig(gf) * c1v + fsig(gi) * ftanh(gg);
        x2c[r][h] = fsig(go) * ftanh(c);
    }
    __syncthreads();
    {   // gates2f: 128 units x 8 rows
        int u = tid & 127;
        int rb = (tid >> 7) * 4;
        float wa[64], wb2[32];
#pragma unroll
        for (int q = 0; q < 16; ++q) {
            float4 a = *(const float4*)&wih2[(size_t)u * 64 + 4 * q];
            wa[4 * q] = a.x; wa[4 * q + 1] = a.y; wa[4 * q + 2] = a.z; wa[4 * q + 3] = a.w;
        }
#pragma unroll
        for (int q = 0; q < 8; ++q) {
            float4 b = *(const float4*)&whh2[(size_t)u * 32 + 4 * q];
            wb2[4 * q] = b.x; wb2[4 * q + 1] = b.y; wb2[4 * q + 2] = b.z; wb2[4 * q + 3] = b.w;
        }
        float bias = bih2[u] + bhh2[u];
        for (int r = rb; r < rb + 4; ++r) {
            float g = bias;
#pragma unroll
            for (int k = 0; k < 64; ++k) g += wa[k] * x2c[r][k];
#pragma unroll
            for (int k = 0; k < 32; ++k) g += wb2[k] * x2c[r][64 + k];
            g2f[r][u] = g;
        }
    }
    __syncthreads();
    {   // fh2 elementwise: 256 tasks
        int r = tid >> 5, v = tid & 31;
        float gi = g2f[r][v], gf = g2f[r][32 + v], gg = g2f[r][64 + v], go = g2f[r][96 + v];
        float c2v = c2_all[(size_t)(R0 + r) * 32 + v];
        float c = fsig(gf) * c2v + fsig(gi) * ftanh(gg);
        fh2s[r][v] = fsig(go) * ftanh(c);
    }
    __syncthreads();
    if (tid < 8) {
        float g = fc8_b[0];
#pragma unroll
        for (int k = 0; k < 32; ++k) g += fh2s[tid][k] * fc8_w[k];
        out_fprog[R0 + tid] = fsig(g);
    }
}

// ---------------- launch ----------------
extern "C" void kernel_launch(void* const* d_in, const int* in_sizes, int n_in,
                              void* d_out, int out_size, void* d_ws, size_t ws_size,
                              hipStream_t stream) {
    (void)in_sizes; (void)n_in; (void)out_size; (void)ws_size;
    const float* frames   = (const float*)d_in[0];
    const float* spp_fc_w = (const float*)d_in[1];
    const float* spp_fc_b = (const float*)d_in[2];
    const float* fc7_w    = (const float*)d_in[3];
    const float* fc7_b    = (const float*)d_in[4];
    const float* l1_wih   = (const float*)d_in[5];
    const float* l1_whh   = (const float*)d_in[6];
    const float* l1_bih   = (const float*)d_in[7];
    const float* l1_bhh   = (const float*)d_in[8];
    const float* l2_wih   = (const float*)d_in[9];
    const float* l2_whh   = (const float*)d_in[10];
    const float* l2_bih   = (const float*)d_in[11];
    const float* l2_bhh   = (const float*)d_in[12];
    const float* fo_w     = (const float*)d_in[13];
    const float* fo_b     = (const float*)d_in[14];
    const float* fc8_w    = (const float*)d_in[15];
    const float* fc8_b    = (const float*)d_in[16];
    float* out = (float*)d_out;
    float* ws  = (float*)d_ws;

    float* pooled = ws + OFF_POOLED;
    float* emb1   = ws + OFF_EMB1;
    float* acc1   = ws + OFF_ACC1;
    float* acc2   = ws + OFF_ACC2;
    float* X1     = ws + OFF_X1;
    float* fpool  = ws + OFF_FPOOL;
    float* h1a    = ws + OFF_H1;
    float* c1a    = ws + OFF_C1;
    float* h2a    = ws + OFF_H2;
    float* c2a    = ws + OFF_C2;

    float* out_prog    = out;
    float* out_fprog   = out + 2048;
    float* out_pooled  = out + 4096;
    float* out_fpooled = out + 188416;

    hipMemsetAsync(acc1, 0, (size_t)262144 * sizeof(float), stream);  // acc1+acc2 contiguous
    spp_kernel<<<6144, 256, 0, stream>>>(frames, out_pooled, pooled);
    gemm90_kernel<<<dim3(16, 32), 256, 0, stream>>>(pooled, spp_fc_w, spp_fc_b, emb1);
    gemmk_kernel<<<dim3(16, 16), 256, 0, stream>>>(emb1, fc7_w, acc1);
    x1_kernel<<<256, 256, 0, stream>>>(acc1, fc7_b, l1_wih, l1_bih, l1_bhh, X1);
    seq_kernel<<<8, 256, 0, stream>>>(X1, l1_whh, l2_wih, l2_whh, l2_bih, l2_bhh, h1a, c1a, h2a, c2a);
    fpool_kernel<<<128, 256, 0, stream>>>(h2a, fo_w, fo_b, fc8_w, fc8_b, fpool, out_fpooled, out_prog);
    gemm90_kernel<<<dim3(16, 32), 256, 0, stream>>>(fpool, spp_fc_w, spp_fc_b, emb1);
    gemmk_kernel<<<dim3(16, 16), 256, 0, stream>>>(emb1, fc7_w, acc2);
    fh_kernel<<<256, 256, 0, stream>>>(acc2, fc7_b, h1a, c1a, h2a, c2a,
                                       l1_wih, l1_whh, l1_bih, l1_bhh,
                                       l2_wih, l2_whh, l2_bih, l2_bhh,
                                       fc8_w, fc8_b, out_fprog);
}

// Round 9
// 668.600 us; speedup vs baseline: 1.2596x; 1.2596x over previous
//
#include <hip/hip_runtime.h>
#include <math.h>

// ---------------- ws layout (floats) ----------------
static const size_t OFF_POOLED = 0;                     // 2048*90
static const size_t OFF_EMB1   = 184320;                // 2048*4096 (reused for fe1)
static const size_t OFF_ACC1   = OFF_EMB1 + 8388608;    // 2048*64
static const size_t OFF_ACC2   = OFF_ACC1 + 131072;     // 2048*64
static const size_t OFF_X1     = OFF_ACC2 + 131072;     // 2048*256
static const size_t OFF_FPOOL  = OFF_X1 + 524288;       // 2048*90
static const size_t OFF_H1     = OFF_FPOOL + 184320;    // 2048*64
static const size_t OFF_C1     = OFF_H1 + 131072;       // 2048*64
static const size_t OFF_H2     = OFF_C1 + 131072;       // 2048*32
static const size_t OFF_C2     = OFF_H2 + 65536;        // 2048*32

typedef _Float16 h2f_t __attribute__((ext_vector_type(2)));

__device__ __forceinline__ float fsig(float x) {
    return __builtin_amdgcn_rcpf(1.0f + __expf(-x));
}
__device__ __forceinline__ float ftanh(float x) {
    return 1.0f - 2.0f * __builtin_amdgcn_rcpf(__expf(2.0f * x) + 1.0f);
}

// f32 += f16x2 · f16x2 (f32 accumulate). v_dot2_f32_f16 on gfx950.
__device__ __forceinline__ float fdot2(h2f_t a, h2f_t b, float c) {
#if __has_builtin(__builtin_amdgcn_fdot2)
    return __builtin_amdgcn_fdot2(a, b, c, false);
#else
    return c + (float)a.x * (float)b.x + (float)a.y * (float)b.y;
#endif
}
__device__ __forceinline__ h2f_t h2pack(float x, float y) {
    h2f_t r; r.x = (_Float16)x; r.y = (_Float16)y; return r;
}
__device__ __forceinline__ h2f_t h2bits(int v) {
    return __builtin_bit_cast(h2f_t, v);
}
// wave-local LDS fence: drains lgkm (LDS visibility) WITHOUT touching vmcnt —
// global stores / prefetch loads stay in flight.
__device__ __forceinline__ void lds_fence() {
    asm volatile("s_waitcnt lgkmcnt(0)" ::: "memory");
}
// gfx950: exchange upper 32 lanes of x with lower 32 lanes of y (VALU, no LDS).
__device__ __forceinline__ void permswap(float& x, float& y) {
    asm volatile("v_permlane32_swap_b32 %0, %1" : "+v"(x), "+v"(y));
}

// ---------------- SPP: adaptive max pool levels 4,3,2,1 ----------------
__global__ __launch_bounds__(256) void spp_kernel(const float* __restrict__ frames,
                                                  float* __restrict__ out_pooled,
                                                  float* __restrict__ ws_pooled) {
    __shared__ __align__(16) float img[9216];
    __shared__ float p4[16], p3[9];
    int blk = blockIdx.x;          // n*3 + c
    int n = blk / 3, c = blk % 3;
    const float* src = frames + (size_t)blk * 9216;
    int tid = threadIdx.x;
    const float4* s4 = (const float4*)src;
    float4* i4 = (float4*)img;
#pragma unroll
    for (int j = 0; j < 9; ++j) i4[tid + 256 * j] = s4[tid + 256 * j];
    __syncthreads();
    // level 4: 16 regions of 24x24; 16 lanes/region read consecutive elements
    {
        int r = tid >> 4, i = tid & 15;
        int ri = r >> 2, rj = r & 3;
        const float* base = &img[(24 * ri) * 96 + 24 * rj];
        float m = -3.402823466e38f;
#pragma unroll 6
        for (int k = 0; k < 36; ++k) {
            int e = i + 16 * k;          // 0..575
            int row = e / 24;
            int col = e - row * 24;
            m = fmaxf(m, base[row * 96 + col]);
        }
#pragma unroll
        for (int sh = 8; sh >= 1; sh >>= 1) m = fmaxf(m, __shfl_xor(m, sh));
        if (i == 0) p4[r] = m;
    }
    // level 3: 9 regions of 32x32; 16 lanes/region, consecutive elements
    if (tid < 144) {
        int r = tid >> 4, i = tid & 15;
        int ri = r / 3, rj = r % 3;
        const float* base = &img[(32 * ri) * 96 + 32 * rj];
        float m = -3.402823466e38f;
#pragma unroll 8
        for (int k = 0; k < 64; ++k) {
            int e = i + 16 * k;          // 0..1023
            int row = e >> 5, col = e & 31;
            m = fmaxf(m, base[row * 96 + col]);
        }
#pragma unroll
        for (int sh = 8; sh >= 1; sh >>= 1) m = fmaxf(m, __shfl_xor(m, sh));
        if (i == 0) p3[r] = m;
    }
    __syncthreads();
    if (tid < 30) {
        float v; int off;
        if (tid < 16) { v = p4[tid]; off = c * 16 + tid; }
        else if (tid < 25) { int q = tid - 16; v = p3[q]; off = 48 + c * 9 + q; }
        else if (tid < 29) {
            int q = tid - 25; int i2 = q >> 1, j2 = q & 1;
            v = fmaxf(fmaxf(p4[(2 * i2) * 4 + 2 * j2], p4[(2 * i2) * 4 + 2 * j2 + 1]),
                      fmaxf(p4[(2 * i2 + 1) * 4 + 2 * j2], p4[(2 * i2 + 1) * 4 + 2 * j2 + 1]));
            off = 75 + c * 4 + q;
        } else {
            float m = p4[0];
#pragma unroll
            for (int q = 1; q < 16; ++q) m = fmaxf(m, p4[q]);
            v = m; off = 87 + c;
        }
        out_pooled[(size_t)n * 90 + off] = v;
        ws_pooled[(size_t)n * 90 + off] = v;
    }
}

// ---------------- GEMM: Y(2048,4096) = relu(X(2048,90) @ W(4096,90)^T + b) ----------------
__global__ __launch_bounds__(256) void gemm90_kernel(const float* __restrict__ X,
                                                     const float* __restrict__ W,
                                                     const float* __restrict__ bias,
                                                     float* __restrict__ Y) {
    __shared__ __align__(16) float Xs[32][132];
    __shared__ __align__(16) float Ws[32][132];
    int tid = threadIdx.x;
    int R0 = blockIdx.x * 128, C0 = blockIdx.y * 128;
    int r0t = (tid >> 4) * 8, c0t = (tid & 15) * 8;
    float acc[8][8];
#pragma unroll
    for (int i = 0; i < 8; ++i)
#pragma unroll
        for (int j = 0; j < 8; ++j) acc[i][j] = 0.f;

    for (int k0 = 0; k0 < 96; k0 += 32) {
#pragma unroll
        for (int j = 0; j < 4; ++j) {
            int idx = tid + 256 * j;
            int row = idx & 127, q = idx >> 7;
            int kg = k0 + 4 * q;
            const float2* p = (const float2*)&X[(size_t)(R0 + row) * 90 + kg];
            float2 a = p[0], b = p[1];
            Xs[4 * q + 0][row] = a.x; Xs[4 * q + 1][row] = a.y;
            Xs[4 * q + 2][row] = b.x; Xs[4 * q + 3][row] = b.y;
        }
#pragma unroll
        for (int j = 0; j < 4; ++j) {
            int idx = tid + 256 * j;
            int col = idx & 127, q = idx >> 7;
            int kg = k0 + 4 * q;
            float v0, v1, v2, v3;
            if (kg + 3 < 90) {
                const float2* p = (const float2*)&W[(size_t)(C0 + col) * 90 + kg];
                float2 a = p[0], b = p[1];
                v0 = a.x; v1 = a.y; v2 = b.x; v3 = b.y;
            } else {
                const float* p = &W[(size_t)(C0 + col) * 90];
                v0 = (kg + 0 < 90) ? p[kg + 0] : 0.f;
                v1 = (kg + 1 < 90) ? p[kg + 1] : 0.f;
                v2 = (kg + 2 < 90) ? p[kg + 2] : 0.f;
                v3 = (kg + 3 < 90) ? p[kg + 3] : 0.f;
            }
            Ws[4 * q + 0][col] = v0; Ws[4 * q + 1][col] = v1;
            Ws[4 * q + 2][col] = v2; Ws[4 * q + 3][col] = v3;
        }
        __syncthreads();
#pragma unroll 8
        for (int kk = 0; kk < 32; ++kk) {
            float4 xa = *(const float4*)&Xs[kk][r0t];
            float4 xb = *(const float4*)&Xs[kk][r0t + 4];
            float4 wa = *(const float4*)&Ws[kk][c0t];
            float4 wb = *(const float4*)&Ws[kk][c0t + 4];
            float xr[8] = {xa.x, xa.y, xa.z, xa.w, xb.x, xb.y, xb.z, xb.w};
            float wc[8] = {wa.x, wa.y, wa.z, wa.w, wb.x, wb.y, wb.z, wb.w};
#pragma unroll
            for (int i = 0; i < 8; ++i)
#pragma unroll
                for (int j = 0; j < 8; ++j) acc[i][j] += xr[i] * wc[j];
        }
        __syncthreads();
    }
    float4 ba = *(const float4*)&bias[C0 + c0t];
    float4 bb = *(const float4*)&bias[C0 + c0t + 4];
    float bs[8] = {ba.x, ba.y, ba.z, ba.w, bb.x, bb.y, bb.z, bb.w};
#pragma unroll
    for (int i = 0; i < 8; ++i) {
        float4 o0, o1;
        o0.x = fmaxf(acc[i][0] + bs[0], 0.f); o0.y = fmaxf(acc[i][1] + bs[1], 0.f);
        o0.z = fmaxf(acc[i][2] + bs[2], 0.f); o0.w = fmaxf(acc[i][3] + bs[3], 0.f);
        o1.x = fmaxf(acc[i][4] + bs[4], 0.f); o1.y = fmaxf(acc[i][5] + bs[5], 0.f);
        o1.z = fmaxf(acc[i][6] + bs[6], 0.f); o1.w = fmaxf(acc[i][7] + bs[7], 0.f);
        *(float4*)&Y[(size_t)(R0 + r0t + i) * 4096 + C0 + c0t] = o0;
        *(float4*)&Y[(size_t)(R0 + r0t + i) * 4096 + C0 + c0t + 4] = o1;
    }
}

// ---------------- GEMM: acc(2048,64) += X(2048,4096) @ W(64,4096)^T, K-split + atomics ----------------
__global__ __launch_bounds__(256) void gemmk_kernel(const float* __restrict__ X,
                                                    const float* __restrict__ W,
                                                    float* __restrict__ acc_out) {
    __shared__ __align__(16) float Xs[32][132];
    __shared__ __align__(16) float Ws[32][68];
    int tid = threadIdx.x;
    int R0 = blockIdx.x * 128;
    int K0 = blockIdx.y * 256;
    int r0t = (tid >> 4) * 8, c0t = (tid & 15) * 4;
    float acc[8][4];
#pragma unroll
    for (int i = 0; i < 8; ++i)
#pragma unroll
        for (int j = 0; j < 4; ++j) acc[i][j] = 0.f;

    for (int k0 = K0; k0 < K0 + 256; k0 += 32) {
#pragma unroll
        for (int j = 0; j < 4; ++j) {
            int idx = tid + 256 * j;
            int row = idx & 127, q = idx >> 7;
            float4 a = *(const float4*)&X[(size_t)(R0 + row) * 4096 + k0 + 4 * q];
            Xs[4 * q + 0][row] = a.x; Xs[4 * q + 1][row] = a.y;
            Xs[4 * q + 2][row] = a.z; Xs[4 * q + 3][row] = a.w;
        }
#pragma unroll
        for (int j = 0; j < 2; ++j) {
            int idx = tid + 256 * j;
            int col = idx & 63, q = idx >> 6;
            float4 a = *(const float4*)&W[(size_t)col * 4096 + k0 + 4 * q];
            Ws[4 * q + 0][col] = a.x; Ws[4 * q + 1][col] = a.y;
            Ws[4 * q + 2][col] = a.z; Ws[4 * q + 3][col] = a.w;
        }
        __syncthreads();
#pragma unroll 8
        for (int kk = 0; kk < 32; ++kk) {
            float4 xa = *(const float4*)&Xs[kk][r0t];
            float4 xb = *(const float4*)&Xs[kk][r0t + 4];
            float4 wa = *(const float4*)&Ws[kk][c0t];
            float xr[8] = {xa.x, xa.y, xa.z, xa.w, xb.x, xb.y, xb.z, xb.w};
            float wc[4] = {wa.x, wa.y, wa.z, wa.w};
#pragma unroll
            for (int i = 0; i < 8; ++i)
#pragma unroll
                for (int j = 0; j < 4; ++j) acc[i][j] += xr[i] * wc[j];
        }
        __syncthreads();
    }
#pragma unroll
    for (int i = 0; i < 8; ++i)
#pragma unroll
        for (int j = 0; j < 4; ++j)
            atomicAdd(&acc_out[(size_t)(R0 + r0t + i) * 64 + c0t + j], acc[i][j]);
}

// ---------------- X1 = relu(acc1 + fc7_b) @ wih1^T + bih1 + bhh1  -> (2048,256) ----------------
__global__ __launch_bounds__(256) void x1_kernel(const float* __restrict__ acc1,
                                                 const float* __restrict__ fc7_b,
                                                 const float* __restrict__ wih1,
                                                 const float* __restrict__ bih1,
                                                 const float* __restrict__ bhh1,
                                                 float* __restrict__ X1) {
    __shared__ __align__(16) float xr[8][64];
    int tid = threadIdx.x;
    int R0 = blockIdx.x * 8;
#pragma unroll
    for (int j = 0; j < 2; ++j) {
        int idx = tid + 256 * j;
        int r = idx >> 6, k = idx & 63;
        xr[r][k] = fmaxf(acc1[(size_t)(R0 + r) * 64 + k] + fc7_b[k], 0.f);
    }
    __syncthreads();
    int u = tid;
    float w[64];
#pragma unroll
    for (int q = 0; q < 16; ++q) {
        float4 a = *(const float4*)&wih1[(size_t)u * 64 + 4 * q];
        w[4 * q] = a.x; w[4 * q + 1] = a.y; w[4 * q + 2] = a.z; w[4 * q + 3] = a.w;
    }
    float bias = bih1[u] + bhh1[u];
    for (int r = 0; r < 8; ++r) {
        float g = bias;
#pragma unroll
        for (int k = 0; k < 64; ++k) g += w[k] * xr[r][k];
        X1[(size_t)(R0 + r) * 256 + u] = g;
    }
}

// ---------------- sequential 2-layer LSTM; TWO WAVES per batch element ----------------
// wave0 = L1 recurrence (whh1, 128 dot2/step), wave1 = L2 (wih2+whh2, 96 dot2/step).
// Each wave's weight set fits in arch VGPRs (no AGPR bounce). One s_barrier/step.
// h1 broadcast via double-buffered LDS: wave0 writes h1(t+1), pre-reads it for its own
// next step BEFORE the barrier (same-wave in-order DS => safe); s_waitcnt lgkmcnt(8)
// retires the older ds_write so wave1 sees it after the barrier.
// wave1: gate exchange via 2x v_permlane32_swap (VALU) instead of __shfl (ds_bpermute).
// wave1 needs NO lgkm fence after its h2h write: same-wave DS is in-order, so the
// pre-read returns fresh data and the compiler's register-hazard wait covers use.
// Structural note (r4-r8 falsified alternatives): step period = critical-wave MAC-inst
// count x ~7cy single-wave issue cadence + ~150cy cell tail. Splitting dots across
// waves pays exchange (barrier+LDS latency) >= savings; co-residency contends issue;
// fma_mix/dot2 rates equal. This 2-wave shape is the fixed point.
__global__ __launch_bounds__(128, 1) void seq_kernel(const float* __restrict__ X1,
                                                     const float* __restrict__ whh1,
                                                     const float* __restrict__ wih2,
                                                     const float* __restrict__ whh2,
                                                     const float* __restrict__ bih2,
                                                     const float* __restrict__ bhh2,
                                                     float* __restrict__ h1_all, float* __restrict__ c1_all,
                                                     float* __restrict__ h2_all, float* __restrict__ c2_all) {
    __shared__ __align__(16) _Float16 h1h[2][64];
    __shared__ __align__(16) _Float16 h2h[32];
    const int tid = threadIdx.x;
    const int l = tid & 63;
    const size_t n0 = (size_t)blockIdx.x * 256;
    const float* xp = X1 + n0 * 256;

    if (tid < 64) {
        // ================= wave 0: layer-1 recurrence =================
        // pack whh1 rows l, 64+l, 128+l, 192+l -> f16 pairs (i,f,g,o in-lane): 128 VGPRs
        h2f_t w1[4][32];
#pragma unroll
        for (int g = 0; g < 4; ++g) {
            const float* wr = whh1 + (size_t)(g * 64 + l) * 64;
#pragma unroll
            for (int q = 0; q < 32; ++q) w1[g][q] = h2pack(wr[2 * q], wr[2 * q + 1]);
        }
        float c1;
        {   // prologue: t=0 from X1 row 0; h1(-1)=c1(-1)=0
            float a0 = xp[l], a1 = xp[64 + l], a2 = xp[128 + l], a3 = xp[192 + l];
            (void)a1;  // f-gate multiplies c1(-1)=0
            c1 = fsig(a0) * ftanh(a2);
            float h1n = fsig(a3) * ftanh(c1);
            h1h[0][l] = (_Float16)h1n;
            h1_all[n0 * 64 + l] = h1n;
            c1_all[n0 * 64 + l] = c1;
        }
        // 2-deep X1 prefetch: xb0 = row 1 (for t=0), xb1 = row 2 (for t=1)
        float xb0[4], xb1[4];
        {
            const float* x1r = xp + 256;
            xb0[0] = x1r[l]; xb0[1] = x1r[64 + l]; xb0[2] = x1r[128 + l]; xb0[3] = x1r[192 + l];
            const float* x2r = xp + 512;
            xb1[0] = x2r[l]; xb1[1] = x2r[64 + l]; xb1[2] = x2r[128 + l]; xb1[3] = x2r[192 + l];
        }
        lds_fence();
        int4 hv[8];   // broadcast read: every lane holds all 64 h1 f16 values
        {
            const int4* hb = (const int4*)&h1h[0][0];
#pragma unroll
            for (int q = 0; q < 8; ++q) hv[q] = hb[q];
        }
        __builtin_amdgcn_s_barrier();

#pragma unroll 2
        for (int t = 0; t < 256; ++t) {
            float* xc = (t & 1) ? xb1 : xb0;
            float a0 = xc[0], a1 = xc[1], a2 = xc[2], a3 = xc[3];
            {   // refill with row t+3 (clamped; tail values unused)
                int tr = (t + 3 < 256) ? (t + 3) : 255;
                const float* xq = xp + (size_t)tr * 256;
                xc[0] = xq[l]; xc[1] = xq[64 + l]; xc[2] = xq[128 + l]; xc[3] = xq[192 + l];
            }
            // 128 dot2, 8 independent chains (a*,b*) of 16 links each
            float b0 = 0.f, b1 = 0.f, b2 = 0.f, b3 = 0.f;
#pragma unroll
            for (int q = 0; q < 8; ++q) {
                int4 v = hv[q];
                h2f_t hh0 = h2bits(v.x), hh1 = h2bits(v.y), hh2 = h2bits(v.z), hh3 = h2bits(v.w);
                a0 = fdot2(w1[0][4 * q], hh0, a0);     a1 = fdot2(w1[1][4 * q], hh0, a1);
                a2 = fdot2(w1[2][4 * q], hh0, a2);     a3 = fdot2(w1[3][4 * q], hh0, a3);
                b0 = fdot2(w1[0][4 * q + 1], hh1, b0); b1 = fdot2(w1[1][4 * q + 1], hh1, b1);
                b2 = fdot2(w1[2][4 * q + 1], hh1, b2); b3 = fdot2(w1[3][4 * q + 1], hh1, b3);
                a0 = fdot2(w1[0][4 * q + 2], hh2, a0); a1 = fdot2(w1[1][4 * q + 2], hh2, a1);
                a2 = fdot2(w1[2][4 * q + 2], hh2, a2); a3 = fdot2(w1[3][4 * q + 2], hh2, a3);
                b0 = fdot2(w1[0][4 * q + 3], hh3, b0); b1 = fdot2(w1[1][4 * q + 3], hh3, b1);
                b2 = fdot2(w1[2][4 * q + 3], hh3, b2); b3 = fdot2(w1[3][4 * q + 3], hh3, b3);
            }
            a0 += b0; a1 += b1; a2 += b2; a3 += b3;
            // L1 cell -> h1(t+1)
            c1 = fsig(a1) * c1 + fsig(a0) * ftanh(a2);
            float h1n = fsig(a3) * ftanh(c1);
            h1h[(t + 1) & 1][l] = (_Float16)h1n;
            if (t < 255) {
                h1_all[(n0 + t + 1) * 64 + l] = h1n;
                c1_all[(n0 + t + 1) * 64 + l] = c1;
            }
            // pre-read own write for next step (in-order DS => returns fresh data);
            // latency overlaps the barrier wait
            {
                const int4* hb = (const int4*)&h1h[(t + 1) & 1][0];
#pragma unroll
                for (int q = 0; q < 8; ++q) hv[q] = hb[q];
            }
            // outstanding DS: 1 write + 8 reads; retire the (older) write so the
            // other wave sees h1(t+1) after the barrier, without draining the reads
            asm volatile("s_waitcnt lgkmcnt(8)" ::: "memory");
            __builtin_amdgcn_s_barrier();
        }
    } else {
        // ================= wave 1: layer-2 =================
        // rows l and 64+l of wih2 (128x64) and whh2 (128x32): 96 VGPRs
        h2f_t w2a[2][32], w2b[2][16];
#pragma unroll
        for (int g = 0; g < 2; ++g) {
            const float* wa = wih2 + (size_t)(g * 64 + l) * 64;
#pragma unroll
            for (int q = 0; q < 32; ++q) w2a[g][q] = h2pack(wa[2 * q], wa[2 * q + 1]);
            const float* wb = whh2 + (size_t)(g * 64 + l) * 32;
#pragma unroll
            for (int q = 0; q < 16; ++q) w2b[g][q] = h2pack(wb[2 * q], wb[2 * q + 1]);
        }
        const float b2a = bih2[l] + bhh2[l];
        const float b2b = bih2[64 + l] + bhh2[64 + l];
        const bool hi = (l >= 32);
        if (l < 32) h2h[l] = (_Float16)0.f;   // h2(-1) = 0
        lds_fence();
        int4 gv[4];   // h2(t-1) broadcast (self-produced; pre-read before barrier)
        {
            const int4* gb = (const int4*)&h2h[0];
#pragma unroll
            for (int q = 0; q < 4; ++q) gv[q] = gb[q];
        }
        float c2 = 0.f;
        __builtin_amdgcn_s_barrier();

        for (int t = 0; t < 256; ++t) {
            // issue h1(t) reads first; w2b dots below run under their latency
            int4 hv[8];
            {
                const int4* hb = (const int4*)&h1h[t & 1][0];
#pragma unroll
                for (int q = 0; q < 8; ++q) hv[q] = hb[q];
            }
            float pa = b2a, pb = b2b, pc = 0.f, pd = 0.f;
            float pe = 0.f, pf = 0.f, pg = 0.f, ph = 0.f;
            // whh2 · h2(t-1): 32 dot2, 4 chains
#pragma unroll
            for (int q = 0; q < 4; ++q) {
                int4 u = gv[q];
                h2f_t gg0 = h2bits(u.x), gg1 = h2bits(u.y), gg2 = h2bits(u.z), gg3 = h2bits(u.w);
                pe = fdot2(w2b[0][4 * q], gg0, pe);     pf = fdot2(w2b[1][4 * q], gg0, pf);
                pg = fdot2(w2b[0][4 * q + 1], gg1, pg); ph = fdot2(w2b[1][4 * q + 1], gg1, ph);
                pe = fdot2(w2b[0][4 * q + 2], gg2, pe); pf = fdot2(w2b[1][4 * q + 2], gg2, pf);
                pg = fdot2(w2b[0][4 * q + 3], gg3, pg); ph = fdot2(w2b[1][4 * q + 3], gg3, ph);
            }
            // wih2 · h1(t): 64 dot2, 4 chains
#pragma unroll
            for (int q = 0; q < 8; ++q) {
                int4 v = hv[q];
                h2f_t hh0 = h2bits(v.x), hh1 = h2bits(v.y), hh2 = h2bits(v.z), hh3 = h2bits(v.w);
                pa = fdot2(w2a[0][4 * q], hh0, pa);     pb = fdot2(w2a[1][4 * q], hh0, pb);
                pa = fdot2(w2a[0][4 * q + 1], hh1, pa); pb = fdot2(w2a[1][4 * q + 1], hh1, pb);
                pc = fdot2(w2a[0][4 * q + 2], hh2, pc); pd = fdot2(w2a[1][4 * q + 2], hh2, pd);
                pc = fdot2(w2a[0][4 * q + 3], hh3, pc); pd = fdot2(w2a[1][4 * q + 3], hh3, pd);
            }
            pa = (pa + pc) + (pe + pg);   // unit l      : i (l<32) / f (l>=32)
            pb = (pb + pd) + (pf + ph);   // unit 64+l   : g (l<32) / o (l>=32)
            // two VALU permlane32_swap deliver all 4 gates to every lane:
            float s1a = pa, s1b = pb;
            permswap(s1a, s1b);           // lane v<32: i,f   lane 32+v: g,o
            float s2a = pb, s2b = pa;
            permswap(s2a, s2b);           // lane v<32: g,o   lane 32+v: i,f
            float gi = hi ? s2a : s1a;
            float gf = hi ? s2b : s1b;
            float gg = hi ? s1a : s2a;
            float go = hi ? s1b : s2b;
            // L2 cell, computed redundantly in both halves (identical inputs)
            c2 = fsig(gf) * c2 + fsig(gi) * ftanh(gg);
            float h2n = fsig(go) * ftanh(c2);
            if (l < 32) {
                h2h[l] = (_Float16)h2n;
                h2_all[(n0 + t) * 32 + l] = h2n;
                c2_all[(n0 + t) * 32 + l] = c2;
            }
            // pre-read h2(t) for next step: same-wave DS is in-order, so this read
            // returns the just-written data with NO lgkm fence; the compiler's
            // register-hazard wait covers first use next iteration.
            {
                const int4* gb = (const int4*)&h2h[0];
#pragma unroll
                for (int q = 0; q < 4; ++q) gv[q] = gb[q];
            }
            __builtin_amdgcn_s_barrier();
        }
    }
}

// ---------------- fpool + progress (parallel over all 2048 rows) ----------------
__global__ __launch_bounds__(256) void fpool_kernel(const float* __restrict__ h2_all,
                                                    const float* __restrict__ fw,
                                                    const float* __restrict__ fb,
                                                    const float* __restrict__ fc8_w,
                                                    const float* __restrict__ fc8_b,
                                                    float* __restrict__ fpool_ws,
                                                    float* __restrict__ out_fpooled,
                                                    float* __restrict__ out_progress) {
    __shared__ __align__(16) float h2t[16][32];
    __shared__ float fwl[2880];
    int tid = threadIdx.x;
    int R0 = blockIdx.x * 16;
#pragma unroll
    for (int j = 0; j < 2; ++j) {
        int idx = tid + 256 * j;
        int r = idx >> 5, k = idx & 31;
        h2t[r][k] = h2_all[(size_t)(R0 + r) * 32 + k];
    }
    for (int idx = tid; idx < 2880; idx += 256) fwl[idx] = fw[idx];
    __syncthreads();
    for (int j = 0; j < 6; ++j) {
        int idx = tid + 256 * j;
        if (idx < 1440) {
            int r = idx / 90, cc = idx % 90;
            float g = fb[cc];
#pragma unroll
            for (int k = 0; k < 32; ++k) g += h2t[r][k] * fwl[cc * 32 + k];
            fpool_ws[(size_t)(R0 + r) * 90 + cc] = g;
            out_fpooled[(size_t)(R0 + r) * 90 + cc] = g;
        }
    }
    if (tid < 16) {
        float g = fc8_b[0];
#pragma unroll
        for (int k = 0; k < 32; ++k) g += h2t[tid][k] * fc8_w[k];
        out_progress[R0 + tid] = fsig(g);
    }
}

// ---------------- forecast LSTM cells + fprogress (parallel over all 2048 rows) ----------------
__global__ __launch_bounds__(256) void fh_kernel(const float* __restrict__ acc2,
                                                 const float* __restrict__ fc7_b,
                                                 const float* __restrict__ h1_all,
                                                 const float* __restrict__ c1_all,
                                                 const float* __restrict__ h2_all,
                                                 const float* __restrict__ c2_all,
                                                 const float* __restrict__ wih1,
                                                 const float* __restrict__ whh1,
                                                 const float* __restrict__ bih1,
                                                 const float* __restrict__ bhh1,
                                                 const float* __restrict__ wih2,
                                                 const float* __restrict__ whh2,
                                                 const float* __restrict__ bih2,
                                                 const float* __restrict__ bhh2,
                                                 const float* __restrict__ fc8_w,
                                                 const float* __restrict__ fc8_b,
                                                 float* __restrict__ out_fprog) {
    __shared__ __align__(16) float xcat[8][128];   // [fe2 | h1]
    __shared__ float g1f[8][256];
    __shared__ __align__(16) float x2c[8][96];     // [fh1 | h2]
    __shared__ float g2f[8][128];
    __shared__ __align__(16) float fh2s[8][32];
    int tid = threadIdx.x;
    int R0 = blockIdx.x * 8;
#pragma unroll
    for (int j = 0; j < 4; ++j) {
        int idx = tid + 256 * j;
        int r = idx >> 7, k = idx & 127;
        float v;
        if (k < 64) v = fmaxf(acc2[(size_t)(R0 + r) * 64 + k] + fc7_b[k], 0.f);
        else v = h1_all[(size_t)(R0 + r) * 64 + (k - 64)];
        xcat[r][k] = v;
    }
    {
        int r = tid >> 5, k = tid & 31;
        x2c[r][64 + k] = h2_all[(size_t)(R0 + r) * 32 + k];
    }
    __syncthreads();
    {   // gates1f: 256 units, thread per unit, 8 rows
        int u = tid;
        float wa[64], wb[64];
#pragma unroll
        for (int q = 0; q < 16; ++q) {
            float4 a = *(const float4*)&wih1[(size_t)u * 64 + 4 * q];
            wa[4 * q] = a.x; wa[4 * q + 1] = a.y; wa[4 * q + 2] = a.z; wa[4 * q + 3] = a.w;
            float4 b = *(const float4*)&whh1[(size_t)u * 64 + 4 * q];
            wb[4 * q] = b.x; wb[4 * q + 1] = b.y; wb[4 * q + 2] = b.z; wb[4 * q + 3] = b.w;
        }
        float bias = bih1[u] + bhh1[u];
        for (int r = 0; r < 8; ++r) {
            float g = bias;
#pragma unroll
            for (int k = 0; k < 64; ++k) g += wa[k] * xcat[r][k];
#pragma unroll
            for (int k = 0; k < 64; ++k) g += wb[k] * xcat[r][64 + k];
            g1f[r][u] = g;
        }
    }
    __syncthreads();
#pragma unroll
    for (int j = 0; j < 2; ++j) {   // fh1 elementwise: 512 tasks
        int idx = tid + 256 * j;
        int r = idx >> 6, h = idx & 63;
        float gi = g1f[r][h], gf = g1f[r][64 + h], gg = g1f[r][128 + h], go = g1f[r][192 + h];
        float c1v = c1_all[(size_t)(R0 + r) * 64 + h];
        float c = fsig(gf) * c1v + fsig(gi) * ftanh(gg);
        x2c[r][h] = fsig(go) * ftanh(c);
    }
    __syncthreads();
    {   // gates2f: 128 units x 8 rows
        int u = tid & 127;
        int rb = (tid >> 7) * 4;
        float wa[64], wb2[32];
#pragma unroll
        for (int q = 0; q < 16; ++q) {
            float4 a = *(const float4*)&wih2[(size_t)u * 64 + 4 * q];
            wa[4 * q] = a.x; wa[4 * q + 1] = a.y; wa[4 * q + 2] = a.z; wa[4 * q + 3] = a.w;
        }
#pragma unroll
        for (int q = 0; q < 8; ++q) {
            float4 b = *(const float4*)&whh2[(size_t)u * 32 + 4 * q];
            wb2[4 * q] = b.x; wb2[4 * q + 1] = b.y; wb2[4 * q + 2] = b.z; wb2[4 * q + 3] = b.w;
        }
        float bias = bih2[u] + bhh2[u];
        for (int r = rb; r < rb + 4; ++r) {
            float g = bias;
#pragma unroll
            for (int k = 0; k < 64; ++k) g += wa[k] * x2c[r][k];
#pragma unroll
            for (int k = 0; k < 32; ++k) g += wb2[k] * x2c[r][64 + k];
            g2f[r][u] = g;
        }
    }
    __syncthreads();
    {   // fh2 elementwise: 256 tasks
        int r = tid >> 5, v = tid & 31;
        float gi = g2f[r][v], gf = g2f[r][32 + v], gg = g2f[r][64 + v], go = g2f[r][96 + v];
        float c2v = c2_all[(size_t)(R0 + r) * 32 + v];
        float c = fsig(gf) * c2v + fsig(gi) * ftanh(gg);
        fh2s[r][v] = fsig(go) * ftanh(c);
    }
    __syncthreads();
    if (tid < 8) {
        float g = fc8_b[0];
#pragma unroll
        for (int k = 0; k < 32; ++k) g += fh2s[tid][k] * fc8_w[k];
        out_fprog[R0 + tid] = fsig(g);
    }
}

// ---------------- launch ----------------
extern "C" void kernel_launch(void* const* d_in, const int* in_sizes, int n_in,
                              void* d_out, int out_size, void* d_ws, size_t ws_size,
                              hipStream_t stream) {
    (void)in_sizes; (void)n_in; (void)out_size; (void)ws_size;
    const float* frames   = (const float*)d_in[0];
    const float* spp_fc_w = (const float*)d_in[1];
    const float* spp_fc_b = (const float*)d_in[2];
    const float* fc7_w    = (const float*)d_in[3];
    const float* fc7_b    = (const float*)d_in[4];
    const float* l1_wih   = (const float*)d_in[5];
    const float* l1_whh   = (const float*)d_in[6];
    const float* l1_bih   = (const float*)d_in[7];
    const float* l1_bhh   = (const float*)d_in[8];
    const float* l2_wih   = (const float*)d_in[9];
    const float* l2_whh   = (const float*)d_in[10];
    const float* l2_bih   = (const float*)d_in[11];
    const float* l2_bhh   = (const float*)d_in[12];
    const float* fo_w     = (const float*)d_in[13];
    const float* fo_b     = (const float*)d_in[14];
    const float* fc8_w    = (const float*)d_in[15];
    const float* fc8_b    = (const float*)d_in[16];
    float* out = (float*)d_out;
    float* ws  = (float*)d_ws;

    float* pooled = ws + OFF_POOLED;
    float* emb1   = ws + OFF_EMB1;
    float* acc1   = ws + OFF_ACC1;
    float* acc2   = ws + OFF_ACC2;
    float* X1     = ws + OFF_X1;
    float* fpool  = ws + OFF_FPOOL;
    float* h1a    = ws + OFF_H1;
    float* c1a    = ws + OFF_C1;
    float* h2a    = ws + OFF_H2;
    float* c2a    = ws + OFF_C2;

    float* out_prog    = out;
    float* out_fprog   = out + 2048;
    float* out_pooled  = out + 4096;
    float* out_fpooled = out + 188416;

    hipMemsetAsync(acc1, 0, (size_t)262144 * sizeof(float), stream);  // acc1+acc2 contiguous
    spp_kernel<<<6144, 256, 0, stream>>>(frames, out_pooled, pooled);
    gemm90_kernel<<<dim3(16, 32), 256, 0, stream>>>(pooled, spp_fc_w, spp_fc_b, emb1);
    gemmk_kernel<<<dim3(16, 16), 256, 0, stream>>>(emb1, fc7_w, acc1);
    x1_kernel<<<256, 256, 0, stream>>>(acc1, fc7_b, l1_wih, l1_bih, l1_bhh, X1);
    seq_kernel<<<8, 128, 0, stream>>>(X1, l1_whh, l2_wih, l2_whh, l2_bih, l2_bhh, h1a, c1a, h2a, c2a);
    fpool_kernel<<<128, 256, 0, stream>>>(h2a, fo_w, fo_b, fc8_w, fc8_b, fpool, out_fpooled, out_prog);
    gemm90_kernel<<<dim3(16, 32), 256, 0, stream>>>(fpool, spp_fc_w, spp_fc_b, emb1);
    gemmk_kernel<<<dim3(16, 16), 256, 0, stream>>>(emb1, fc7_w, acc2);
    fh_kernel<<<256, 256, 0, stream>>>(acc2, fc7_b, h1a, c1a, h2a, c2a,
                                       l1_wih, l1_whh, l1_bih, l1_bhh,
                                       l2_wih, l2_whh, l2_bih, l2_bhh,
                                       fc8_w, fc8_b, out_fprog);
}